// Round 3
// baseline (18023.683 us; speedup 1.0000x reference)
//
#include <hip/hip_runtime.h>
#include <hip/hip_bf16.h>

#define T_STEPS 2048
#define NB      64
#define IN_DIM  300
#define HID     512

typedef __attribute__((ext_vector_type(8))) short short8;   // 8 bf16 (4 VGPR)
typedef __attribute__((ext_vector_type(4))) float f32x4;    // MFMA accumulator

static __device__ __forceinline__ unsigned short f2bf(float x) {
    unsigned int u = __float_as_uint(x);
    u = u + 0x7FFFu + ((u >> 16) & 1u);          // round-to-nearest-even
    return (unsigned short)(u >> 16);
}
static __device__ __forceinline__ float bf2f(unsigned short h) {
    return __uint_as_float(((unsigned int)h) << 16);
}

// ---------------------------------------------------------------------------
// Kernel 1: U = bf16( x_t W_ih^T + b_ih + b_hh ), written in rec-fragment
// order: U[t][g(4)][jt(32)][lane(64)][r(4)]  (g=b>>4, lane=(m>>2)<<4|jc, r=m&3)
// so rnn_rec loads one coalesced dwordx2 per (lane, col-tile).
// ---------------------------------------------------------------------------
__global__ __launch_bounds__(256, 4) void u_gemm(
    const float* __restrict__ X, const float* __restrict__ Wih,
    const float* __restrict__ bih, const float* __restrict__ bhh,
    unsigned short* __restrict__ U)
{
    __shared__ unsigned short As[64 * 160];
    __shared__ unsigned short Bs[64 * 160];
    const int tid = threadIdx.x;
    const int m0 = (blockIdx.x >> 3) * 64, n0 = (blockIdx.x & 7) * 64;
    const int w = tid >> 6, l = tid & 63;

    const f32x4 zv = {0.f, 0.f, 0.f, 0.f};
    f32x4 acc00 = zv, acc01 = zv, acc10 = zv, acc11 = zv;

    for (int kh = 0; kh < 2; ++kh) {
        const int kbase = kh * 160;
        __syncthreads();
        for (int i = tid; i < 64 * 40; i += 256) {
            const int r = i / 40, q = i - r * 40;
            const int kg = kbase + q * 4;
            unsigned int a0 = 0, a1 = 0, b0 = 0, b1 = 0;
            if (kg + 4 <= IN_DIM) {
                const float4 v = *reinterpret_cast<const float4*>(X + (size_t)(m0 + r) * IN_DIM + kg);
                a0 = (unsigned)f2bf(v.x) | ((unsigned)f2bf(v.y) << 16);
                a1 = (unsigned)f2bf(v.z) | ((unsigned)f2bf(v.w) << 16);
                const float4 u = *reinterpret_cast<const float4*>(Wih + (size_t)(n0 + r) * IN_DIM + kg);
                b0 = (unsigned)f2bf(u.x) | ((unsigned)f2bf(u.y) << 16);
                b1 = (unsigned)f2bf(u.z) | ((unsigned)f2bf(u.w) << 16);
            }
            int byte = r * 320 + q * 8; byte ^= ((r & 7) << 4);
            *reinterpret_cast<uint2*>(reinterpret_cast<char*>(As) + byte) = make_uint2(a0, a1);
            *reinterpret_cast<uint2*>(reinterpret_cast<char*>(Bs) + byte) = make_uint2(b0, b1);
        }
        __syncthreads();
        #pragma unroll
        for (int kc = 0; kc < 5; ++kc) {
            const int koff = kc * 64 + (l >> 4) * 16;
            short8 a[2], b[2];
            #pragma unroll
            for (int mt = 0; mt < 2; ++mt) {
                const int row = (w >> 1) * 32 + mt * 16 + (l & 15);
                int abyte = row * 320 + koff; abyte ^= ((row & 7) << 4);
                a[mt] = *reinterpret_cast<const short8*>(reinterpret_cast<const char*>(As) + abyte);
                const int jrow = (w & 1) * 32 + mt * 16 + (l & 15);
                int bbyte = jrow * 320 + koff; bbyte ^= ((jrow & 7) << 4);
                b[mt] = *reinterpret_cast<const short8*>(reinterpret_cast<const char*>(Bs) + bbyte);
            }
            acc00 = __builtin_amdgcn_mfma_f32_16x16x32_bf16(a[0], b[0], acc00, 0, 0, 0);
            acc01 = __builtin_amdgcn_mfma_f32_16x16x32_bf16(a[0], b[1], acc01, 0, 0, 0);
            acc10 = __builtin_amdgcn_mfma_f32_16x16x32_bf16(a[1], b[0], acc10, 0, 0, 0);
            acc11 = __builtin_amdgcn_mfma_f32_16x16x32_bf16(a[1], b[1], acc11, 0, 0, 0);
        }
    }
    const int t = blockIdx.x >> 3;
    #pragma unroll
    for (int nt = 0; nt < 2; ++nt) {
        const int col = n0 + (w & 1) * 32 + nt * 16 + (l & 15);
        const float bias = bih[col] + bhh[col];
        const int jt = col >> 4;
        #pragma unroll
        for (int mt = 0; mt < 2; ++mt) {
            const f32x4 acc = (mt == 0) ? (nt == 0 ? acc00 : acc01)
                                        : (nt == 0 ? acc10 : acc11);
            const int g = (w >> 1) * 2 + mt;        // batch-group 0..3
            const size_t idx = ((((size_t)t * 4 + g) * 32 + jt) * 64 + l) * 4;
            uint2 p;
            p.x = (unsigned)f2bf(acc[0] + bias) | ((unsigned)f2bf(acc[1] + bias) << 16);
            p.y = (unsigned)f2bf(acc[2] + bias) | ((unsigned)f2bf(acc[3] + bias) << 16);
            *reinterpret_cast<uint2*>(U + idx) = p;
        }
    }
}

// ---------------------------------------------------------------------------
// Kernel 2: recurrence. 4 groups (16 batches each) x 2 blocks (256 cols each).
// Pair {g, g+8} -> same XCD by round-robin heuristic (speed only; correctness
// via agent-scope atomics). ALL weights register-stationary: 32 short8 =
// 128 VGPR/lane (+~45 live), cap 256 via __launch_bounds__(512,1).
// Exchange: self-validating tagged words (tag<<16|bf16), parity double-
// buffered, relaxed agent atomics, NO fences. Poll latency hidden under the
// own-k-half MFMA phase. 2 barriers/step.
// ---------------------------------------------------------------------------
__global__ __launch_bounds__(512, 1) void rnn_rec(
    const float* __restrict__ Whh, const unsigned short* __restrict__ Uf,
    float* __restrict__ out, unsigned int* __restrict__ xbuf)
{
    const int bx = blockIdx.x;
    const int g = bx & 7;
    if (g >= 4) return;                  // 8 working blocks of 16
    const int half = bx >> 3;            // 0 or 1: cols half*256..half*256+255
    const int tid = threadIdx.x;
    const int w = tid >> 6, l = tid & 63;
    const int lq = l >> 4, lr = l & 15;

    __shared__ unsigned short h_lds[16 * 512];   // 16 KB, XOR-swizzled rows

    // --- stationary weights: wave w owns col tiles {2w, 2w+1} of this half
    short8 bfr0[16], bfr1[16];
    const int j0 = half * 256 + (2 * w) * 16 + lr;
    const int j1 = j0 + 16;
    #pragma unroll
    for (int kc = 0; kc < 16; ++kc) {
        const int k0 = kc * 32 + lq * 8;
        {
            const float4 v0 = *reinterpret_cast<const float4*>(Whh + (size_t)j0 * HID + k0);
            const float4 v1 = *reinterpret_cast<const float4*>(Whh + (size_t)j0 * HID + k0 + 4);
            short8 f;
            f[0] = (short)f2bf(v0.x); f[1] = (short)f2bf(v0.y);
            f[2] = (short)f2bf(v0.z); f[3] = (short)f2bf(v0.w);
            f[4] = (short)f2bf(v1.x); f[5] = (short)f2bf(v1.y);
            f[6] = (short)f2bf(v1.z); f[7] = (short)f2bf(v1.w);
            bfr0[kc] = f;
        }
        {
            const float4 v0 = *reinterpret_cast<const float4*>(Whh + (size_t)j1 * HID + k0);
            const float4 v1 = *reinterpret_cast<const float4*>(Whh + (size_t)j1 * HID + k0 + 4);
            short8 f;
            f[0] = (short)f2bf(v0.x); f[1] = (short)f2bf(v0.y);
            f[2] = (short)f2bf(v0.z); f[3] = (short)f2bf(v0.w);
            f[4] = (short)f2bf(v1.x); f[5] = (short)f2bf(v1.y);
            f[6] = (short)f2bf(v1.z); f[7] = (short)f2bf(v1.w);
            bfr1[kc] = f;
        }
    }

    // --- h0 = 0
    for (int i = tid * 8; i < 16 * 512; i += 512 * 8)
        *reinterpret_cast<uint4*>(&h_lds[i]) = make_uint4(0, 0, 0, 0);
    __syncthreads();

    // --- exchange buffers: xbuf[g][member][parity][4096 words]
    unsigned int* own = xbuf + (((size_t)g * 2 + half) * 2) * 4096;
    unsigned int* peer = xbuf + (((size_t)g * 2 + (half ^ 1)) * 2) * 4096;
    const int phofs = (half ^ 1) * 256;          // peer global col base

    const int abase = lr * 1024 + lq * 16;       // A-read: row=lr, col byte lq*16
    const int aswz  = (lr & 7) << 4;
    const char* hcr = reinterpret_cast<const char*>(h_lds);
    char* hcw = reinterpret_cast<char*>(h_lds);
    const int kc_own  = half * 8;                // own cols  -> k chunks
    const int kc_peer = (half ^ 1) * 8;
    const int relc0 = (2 * w) * 16 + lr;         // own relative cols
    const size_t ubase = ((size_t)g * 32 + half * 16 + 2 * w) * 64 * 4 + (size_t)l * 4;
    const int m4 = lq * 4;

    for (int t = 0; t < T_STEPS; ++t) {
        // current-step U (hidden under MFMA phases)
        const unsigned short* up = Uf + (size_t)t * 32768 + ubase;
        const uint2 u0 = *reinterpret_cast<const uint2*>(up);
        const uint2 u1 = *reinterpret_cast<const uint2*>(up + 256);

        // issue poll loads for peer h(t) (latency under own-k MFMAs)
        unsigned int pv[8];
        unsigned int* pp = peer + (size_t)(t & 1) * 4096;
        if (t > 0) {
            #pragma unroll
            for (int j = 0; j < 8; ++j)
                pv[j] = __hip_atomic_load(pp + tid + j * 512,
                                          __ATOMIC_RELAXED, __HIP_MEMORY_SCOPE_AGENT);
        }

        // --- own-k-half MFMA (h values produced locally last step)
        f32x4 acc0 = {0.f, 0.f, 0.f, 0.f};
        f32x4 acc1 = {0.f, 0.f, 0.f, 0.f};
        #pragma unroll
        for (int q = 0; q < 8; ++q) {
            const int kc = kc_own + q;
            const int byte = (abase + kc * 64) ^ aswz;
            const short8 a = *reinterpret_cast<const short8*>(hcr + byte);
            acc0 = __builtin_amdgcn_mfma_f32_16x16x32_bf16(a, bfr0[kc], acc0, 0, 0, 0);
            acc1 = __builtin_amdgcn_mfma_f32_16x16x32_bf16(a, bfr1[kc], acc1, 0, 0, 0);
        }

        // --- finish poll, scatter peer h(t) into LDS
        if (t > 0) {
            const unsigned int tagw = (unsigned int)t << 16;
            #pragma unroll
            for (int j = 0; j < 8; ++j) {
                const int p = tid + j * 512;
                unsigned int v = pv[j];
                while ((v & 0xFFFF0000u) != tagw)
                    v = __hip_atomic_load(pp + p, __ATOMIC_RELAXED, __HIP_MEMORY_SCOPE_AGENT);
                const int m = p >> 8, col = phofs + (p & 255);
                const int byte = (m * 1024 + col * 2) ^ ((m & 7) << 4);
                *reinterpret_cast<unsigned short*>(hcw + byte) = (unsigned short)(v & 0xFFFFu);
            }
        }
        __syncthreads();   // peer half of h(t) in LDS; own reads of h(t) done

        // --- peer-k-half MFMA
        #pragma unroll
        for (int q = 0; q < 8; ++q) {
            const int kc = kc_peer + q;
            const int byte = (abase + kc * 64) ^ aswz;
            const short8 a = *reinterpret_cast<const short8*>(hcr + byte);
            acc0 = __builtin_amdgcn_mfma_f32_16x16x32_bf16(a, bfr0[kc], acc0, 0, 0, 0);
            acc1 = __builtin_amdgcn_mfma_f32_16x16x32_bf16(a, bfr1[kc], acc1, 0, 0, 0);
        }

        // --- tanh(acc + u)
        float th0[4], th1[4];
        #pragma unroll
        for (int r = 0; r < 4; ++r) {
            const unsigned short ub0 = (r < 2) ? (unsigned short)(u0.x >> (16 * r))
                                               : (unsigned short)(u0.y >> (16 * (r - 2)));
            const unsigned short ub1 = (r < 2) ? (unsigned short)(u1.x >> (16 * r))
                                               : (unsigned short)(u1.y >> (16 * (r - 2)));
            const float x0 = acc0[r] + bf2f(ub0);
            const float x1 = acc1[r] + bf2f(ub1);
            th0[r] = 1.f - 2.f / (__expf(2.f * x0) + 1.f);
            th1[r] = 1.f - 2.f / (__expf(2.f * x1) + 1.f);
        }

        if (t == T_STEPS - 1) {
            #pragma unroll
            for (int r = 0; r < 4; ++r) {
                out[(size_t)(g * 16 + m4 + r) * HID + j0] = th0[r];
                out[(size_t)(g * 16 + m4 + r) * HID + j1] = th1[r];
            }
            return;
        }

        // --- publish h(t+1): tagged words (fire-and-forget) + own LDS half
        unsigned int* op = own + (size_t)((t + 1) & 1) * 4096;
        const unsigned int ntag = (unsigned int)(t + 1) << 16;
        #pragma unroll
        for (int r = 0; r < 4; ++r) {
            const int m = m4 + r;
            const unsigned short hb0 = f2bf(th0[r]);
            const unsigned short hb1 = f2bf(th1[r]);
            __hip_atomic_store(op + m * 256 + relc0, ntag | hb0,
                               __ATOMIC_RELAXED, __HIP_MEMORY_SCOPE_AGENT);
            __hip_atomic_store(op + m * 256 + relc0 + 16, ntag | hb1,
                               __ATOMIC_RELAXED, __HIP_MEMORY_SCOPE_AGENT);
            const int swz = (m & 7) << 4;
            *reinterpret_cast<unsigned short*>(hcw + ((m * 1024 + j0 * 2) ^ swz)) = hb0;
            *reinterpret_cast<unsigned short*>(hcw + ((m * 1024 + j1 * 2) ^ swz)) = hb1;
        }
        __syncthreads();   // h(t+1) own half visible; peer-MFMA reads done
    }
}

// ---------------------------------------------------------------------------
extern "C" void kernel_launch(void* const* d_in, const int* in_sizes, int n_in,
                              void* d_out, int out_size, void* d_ws, size_t ws_size,
                              hipStream_t stream) {
    const float* X   = (const float*)d_in[0];   // [2048][64][300]
    const float* Wih = (const float*)d_in[1];   // [512][300]
    const float* Whh = (const float*)d_in[2];   // [512][512]
    const float* bih = (const float*)d_in[3];   // [512]
    const float* bhh = (const float*)d_in[4];   // [512]
    float* out = (float*)d_out;                 // [64][512]
    char* ws = (char*)d_ws;
    // ws layout: [0, 128MB) U bf16 fragment order | [128MB, +256KB) tagged xbuf
    unsigned short* U  = (unsigned short*)ws;
    unsigned int* xbuf = (unsigned int*)(ws + (size_t)T_STEPS * NB * HID * 2);

    hipMemsetAsync(xbuf, 0, 4 * 2 * 2 * 4096 * sizeof(unsigned int), stream);
    u_gemm<<<dim3(2048 * 8), dim3(256), 0, stream>>>(X, Wih, bih, bhh, U);
    rnn_rec<<<dim3(16), dim3(512), 0, stream>>>(Whh, U, out, xbuf);
}

// Round 4
// 6052.346 us; speedup vs baseline: 2.9780x; 2.9780x over previous
//
#include <hip/hip_runtime.h>
#include <hip/hip_bf16.h>

#define T_STEPS 2048
#define NB      64
#define IN_DIM  300
#define HID     512

typedef __attribute__((ext_vector_type(8))) short short8;   // 8 bf16 (4 VGPR)
typedef __attribute__((ext_vector_type(4))) float f32x4;    // MFMA accumulator

static __device__ __forceinline__ unsigned short f2bf(float x) {
    unsigned int u = __float_as_uint(x);
    u = u + 0x7FFFu + ((u >> 16) & 1u);          // round-to-nearest-even
    return (unsigned short)(u >> 16);
}
static __device__ __forceinline__ unsigned cvtpk(float lo, float hi) {
    unsigned r;
    asm("v_cvt_pk_bf16_f32 %0, %1, %2" : "=v"(r) : "v"(lo), "v"(hi));
    return r;
}
static __device__ __forceinline__ short8 pack8(float4 v0, float4 v1) {
    union { unsigned u[4]; short8 s; } x;
    x.u[0] = cvtpk(v0.x, v0.y); x.u[1] = cvtpk(v0.z, v0.w);
    x.u[2] = cvtpk(v1.x, v1.y); x.u[3] = cvtpk(v1.z, v1.w);
    return x.s;
}

// ---------------------------------------------------------------------------
// Kernel 1: U = bf16( x_t W_ih^T + b_ih + b_hh ), D[j][m] orientation, written
// in rec-lane order: U3[t][g(4)][w(8)][lane(64)][c(4)][r(4)] bf16 so each rec
// lane loads its 16 values as 2 contiguous dwordx4.
//   value(t,g,w,l=(lq,lr),c,r) = pre[b = g*16+lr][j = (4w+c)*16 + 4*lq + r]
// ---------------------------------------------------------------------------
__global__ __launch_bounds__(256, 4) void u_gemm(
    const float* __restrict__ X, const float* __restrict__ Wih,
    const float* __restrict__ bih, const float* __restrict__ bhh,
    unsigned short* __restrict__ U3)
{
    __shared__ unsigned short As[64 * 160];   // X rows (batch m)
    __shared__ unsigned short Bs[64 * 160];   // Wih rows (j)
    const int tid = threadIdx.x;
    const int m0 = (blockIdx.x >> 3) * 64, n0 = (blockIdx.x & 7) * 64;
    const int w = tid >> 6, l = tid & 63;
    const int lq = l >> 4, lr = l & 15;

    const f32x4 zv = {0.f, 0.f, 0.f, 0.f};
    f32x4 acc[2][2] = {{zv, zv}, {zv, zv}};   // [jt][mt]

    for (int kh = 0; kh < 2; ++kh) {
        const int kbase = kh * 160;
        __syncthreads();
        for (int i = tid; i < 64 * 40; i += 256) {
            const int r = i / 40, q = i - r * 40;
            const int kg = kbase + q * 4;
            unsigned int a0 = 0, a1 = 0, b0 = 0, b1 = 0;
            if (kg + 4 <= IN_DIM) {
                const float4 v = *reinterpret_cast<const float4*>(X + (size_t)(m0 + r) * IN_DIM + kg);
                a0 = (unsigned)f2bf(v.x) | ((unsigned)f2bf(v.y) << 16);
                a1 = (unsigned)f2bf(v.z) | ((unsigned)f2bf(v.w) << 16);
                const float4 u = *reinterpret_cast<const float4*>(Wih + (size_t)(n0 + r) * IN_DIM + kg);
                b0 = (unsigned)f2bf(u.x) | ((unsigned)f2bf(u.y) << 16);
                b1 = (unsigned)f2bf(u.z) | ((unsigned)f2bf(u.w) << 16);
            }
            int byte = r * 320 + q * 8; byte ^= ((r & 7) << 4);
            *reinterpret_cast<uint2*>(reinterpret_cast<char*>(As) + byte) = make_uint2(a0, a1);
            *reinterpret_cast<uint2*>(reinterpret_cast<char*>(Bs) + byte) = make_uint2(b0, b1);
        }
        __syncthreads();
        #pragma unroll
        for (int kc = 0; kc < 5; ++kc) {
            const int koff = kc * 64 + lq * 16;
            short8 xa[2], wb[2];
            #pragma unroll
            for (int mt = 0; mt < 2; ++mt) {
                const int row = (w >> 1) * 32 + mt * 16 + lr;       // X row (m)
                int abyte = row * 320 + koff; abyte ^= ((row & 7) << 4);
                xa[mt] = *reinterpret_cast<const short8*>(reinterpret_cast<const char*>(As) + abyte);
                const int jrow = (w & 1) * 32 + mt * 16 + lr;       // W row (j)
                int bbyte = jrow * 320 + koff; bbyte ^= ((jrow & 7) << 4);
                wb[mt] = *reinterpret_cast<const short8*>(reinterpret_cast<const char*>(Bs) + bbyte);
            }
            #pragma unroll
            for (int jt = 0; jt < 2; ++jt)
                #pragma unroll
                for (int mt = 0; mt < 2; ++mt)
                    acc[jt][mt] = __builtin_amdgcn_mfma_f32_16x16x32_bf16(
                        wb[jt], xa[mt], acc[jt][mt], 0, 0, 0);
        }
    }
    const int t = blockIdx.x >> 3;
    #pragma unroll
    for (int jt = 0; jt < 2; ++jt) {
        const int jb = n0 + (w & 1) * 32 + jt * 16 + 4 * lq;        // 4 consecutive j
        const float4 b1v = *reinterpret_cast<const float4*>(bih + jb);
        const float4 b2v = *reinterpret_cast<const float4*>(bhh + jb);
        const float4 bv = {b1v.x + b2v.x, b1v.y + b2v.y, b1v.z + b2v.z, b1v.w + b2v.w};
        const int jtg = jb >> 4;
        const int wv2 = jtg >> 2, cc = jtg & 3;
        #pragma unroll
        for (int mt = 0; mt < 2; ++mt) {
            const int b = (w >> 1) * 32 + mt * 16 + lr;             // batch row
            const int g = b >> 4, lrr = b & 15;
            const f32x4 a = acc[jt][mt];
            uint2 p;
            p.x = cvtpk(a[0] + bv.x, a[1] + bv.y);
            p.y = cvtpk(a[2] + bv.z, a[3] + bv.w);
            const size_t sidx = ((((size_t)t * 4 + g) * 8 + wv2) * 64 + (lq * 16 + lrr)) * 16 + cc * 4;
            *reinterpret_cast<uint2*>(U3 + sidx) = p;
        }
    }
}

// ---------------------------------------------------------------------------
// Kernel 2: recurrence, zero inter-block traffic. 4 blocks x 512 thr; block g
// owns batches g*16..+16, all 512 cols. D[j][m] orientation: A = W_hh
// (stationary: kc 0..11 in VGPR [192 regs, static idx], kc 12..15 in LDS
// 128KB), B = h fragments from 16KB XOR-swizzled LDS. Per step: 64 MFMA/wave,
// 16 B-frag + 16 W-frag ds_read_b128 + 4 ds_write_b64 per wave, 2 barriers.
// ---------------------------------------------------------------------------
__global__ __launch_bounds__(512) __attribute__((amdgpu_waves_per_eu(2, 2)))
void rnn_rec(const float* __restrict__ Whh, const unsigned short* __restrict__ U3,
             float* __restrict__ out)
{
    const int g = blockIdx.x;                // 0..3
    const int tid = threadIdx.x;
    const int w = tid >> 6, l = tid & 63;
    const int lq = l >> 4, lr = l & 15;

    __shared__ unsigned short h_lds[16 * 512];          // 16 KB  [m][col]
    __shared__ unsigned short w_lds[4 * 32 * 64 * 8];   // 128 KB [kp][jt][lane][8]

    // --- stationary VGPR weights: A-frag W[j=(4w+c)*16+lr][k=kc*32+lq*8+e]
    short8 wv[4][12];
    #pragma unroll
    for (int c = 0; c < 4; ++c) {
        const float* wr = Whh + (size_t)((4 * w + c) * 16 + lr) * HID;
        #pragma unroll
        for (int kc = 0; kc < 12; ++kc) {
            const int k0 = kc * 32 + lq * 8;
            wv[c][kc] = pack8(*reinterpret_cast<const float4*>(wr + k0),
                              *reinterpret_cast<const float4*>(wr + k0 + 4));
        }
    }
    // --- LDS weights kc 12..15 (each wave fills only its own 4 j-tiles)
    #pragma unroll
    for (int kp = 0; kp < 4; ++kp)
        #pragma unroll
        for (int c = 0; c < 4; ++c) {
            const float* wr = Whh + (size_t)((4 * w + c) * 16 + lr) * HID;
            const int k0 = (12 + kp) * 32 + lq * 8;
            *reinterpret_cast<short8*>(&w_lds[(((size_t)kp * 32 + (4 * w + c)) * 64 + l) * 8]) =
                pack8(*reinterpret_cast<const float4*>(wr + k0),
                      *reinterpret_cast<const float4*>(wr + k0 + 4));
        }
    // --- h0 = 0
    for (int i = tid * 8; i < 16 * 512; i += 512 * 8)
        *reinterpret_cast<uint4*>(&h_lds[i]) = make_uint4(0, 0, 0, 0);
    __syncthreads();

    // --- precomputed addresses (all t-invariant)
    const int swz = (lr & 7) << 4;
    const int baseE = (lr * 1024 + lq * 16) ^ swz;        // even kc: + (kc>>1)*128
    const int baseO = (lr * 1024 + 64 + lq * 16) ^ swz;   // odd  kc: + (kc>>1)*128
    const int wbase = w * 4096 + l * 16;                  // + kp*32768 + c*1024
    int wrA[4];
    #pragma unroll
    for (int c = 0; c < 4; ++c)
        wrA[c] = (lr * 1024 + (4 * w + c) * 32 + lq * 8) ^ swz;
    const unsigned short* uptr = U3 + ((size_t)(g * 8 + w) * 64 + l) * 16;

    const char* hc = reinterpret_cast<const char*>(h_lds);
    char* hw = reinterpret_cast<char*>(h_lds);
    const char* wc = reinterpret_cast<const char*>(w_lds);

    #pragma unroll 1
    for (int t = 0; t < T_STEPS; ++t) {
        const uint4 ua = *reinterpret_cast<const uint4*>(uptr);       // c=0,1
        const uint4 ub = *reinterpret_cast<const uint4*>(uptr + 8);   // c=2,3
        uptr += 32768;

        f32x4 acc[4] = {{0.f, 0.f, 0.f, 0.f}, {0.f, 0.f, 0.f, 0.f},
                        {0.f, 0.f, 0.f, 0.f}, {0.f, 0.f, 0.f, 0.f}};
        #pragma unroll
        for (int kc = 0; kc < 12; ++kc) {
            const int hb_off = ((kc & 1) ? baseO : baseE) + (kc >> 1) * 128;
            const short8 hb = *reinterpret_cast<const short8*>(hc + hb_off);
            #pragma unroll
            for (int c = 0; c < 4; ++c)
                acc[c] = __builtin_amdgcn_mfma_f32_16x16x32_bf16(wv[c][kc], hb, acc[c], 0, 0, 0);
        }
        #pragma unroll
        for (int kp = 0; kp < 4; ++kp) {
            const int kc = 12 + kp;
            const int hb_off = ((kc & 1) ? baseO : baseE) + (kc >> 1) * 128;
            const short8 hb = *reinterpret_cast<const short8*>(hc + hb_off);
            #pragma unroll
            for (int c = 0; c < 4; ++c) {
                const short8 wa = *reinterpret_cast<const short8*>(
                    wc + (wbase + kp * 32768 + c * 1024));
                acc[c] = __builtin_amdgcn_mfma_f32_16x16x32_bf16(wa, hb, acc[c], 0, 0, 0);
            }
        }

        // --- tanh(acc + u): th[c][r], j = (4w+c)*16 + 4lq + r, m = lr
        float th[4][4];
        #pragma unroll
        for (int c = 0; c < 4; ++c) {
            const unsigned w0 = (c == 0) ? ua.x : (c == 1) ? ua.z : (c == 2) ? ub.x : ub.z;
            const unsigned w1 = (c == 0) ? ua.y : (c == 1) ? ua.w : (c == 2) ? ub.y : ub.w;
            #pragma unroll
            for (int r = 0; r < 4; ++r) {
                const unsigned word = (r < 2) ? w0 : w1;
                const float uf = __uint_as_float((r & 1) ? (word & 0xFFFF0000u) : (word << 16));
                const float x = acc[c][r] + uf;
                const float e = __expf(2.f * x);
                th[c][r] = 1.f - __fdividef(2.f, e + 1.f);
            }
        }

        if (t == T_STEPS - 1) {
            #pragma unroll
            for (int c = 0; c < 4; ++c) {
                const float4 o = {th[c][0], th[c][1], th[c][2], th[c][3]};
                *reinterpret_cast<float4*>(out + (size_t)(g * 16 + lr) * HID +
                                           (4 * w + c) * 16 + 4 * lq) = o;
            }
            return;
        }

        __syncthreads();   // all B-frag reads of h(t) complete
        #pragma unroll
        for (int c = 0; c < 4; ++c) {
            const uint2 p = make_uint2(cvtpk(th[c][0], th[c][1]), cvtpk(th[c][2], th[c][3]));
            *reinterpret_cast<uint2*>(hw + wrA[c]) = p;    // ds_write_b64
        }
        __syncthreads();   // h(t+1) visible
    }
}

// ---------------------------------------------------------------------------
extern "C" void kernel_launch(void* const* d_in, const int* in_sizes, int n_in,
                              void* d_out, int out_size, void* d_ws, size_t ws_size,
                              hipStream_t stream) {
    const float* X   = (const float*)d_in[0];   // [2048][64][300]
    const float* Wih = (const float*)d_in[1];   // [512][300]
    const float* Whh = (const float*)d_in[2];   // [512][512]
    const float* bih = (const float*)d_in[3];   // [512]
    const float* bhh = (const float*)d_in[4];   // [512]
    float* out = (float*)d_out;                 // [64][512]
    unsigned short* U3 = (unsigned short*)d_ws; // 128 MB, rec-lane order

    u_gemm<<<dim3(2048 * 8), dim3(256), 0, stream>>>(X, Wih, bih, bhh, U3);
    rnn_rec<<<dim3(4), dim3(512), 0, stream>>>(Whh, U3, out);
}

// Round 5
// 4113.908 us; speedup vs baseline: 4.3812x; 1.4712x over previous
//
#include <hip/hip_runtime.h>
#include <hip/hip_bf16.h>

#define T_STEPS 2048
#define NB      64
#define IN_DIM  300
#define HID     512

typedef __attribute__((ext_vector_type(8))) short short8;   // 8 bf16 (4 VGPR)
typedef __attribute__((ext_vector_type(4))) float f32x4;    // MFMA f32 accum
typedef __attribute__((ext_vector_type(4))) int   i32x4;    // MFMA i8 frag/accum

static __device__ __forceinline__ unsigned short f2bf(float x) {
    unsigned int u = __float_as_uint(x);
    u = u + 0x7FFFu + ((u >> 16) & 1u);          // round-to-nearest-even
    return (unsigned short)(u >> 16);
}
static __device__ __forceinline__ unsigned cvtpk(float lo, float hi) {
    unsigned r;
    asm("v_cvt_pk_bf16_f32 %0, %1, %2" : "=v"(r) : "v"(lo), "v"(hi));
    return r;
}

// ---------------------------------------------------------------------------
// Kernel 1: U = bf16( x_t W_ih^T + b_ih + b_hh ), D[j][m] orientation, written
// in rec-lane order: U3[t][g(4)][w(8)][lane(64)][c(4)][r(4)] bf16 so each rec
// lane loads its 16 values as 2 contiguous dwordx4.  (unchanged from R4)
// ---------------------------------------------------------------------------
__global__ __launch_bounds__(256, 4) void u_gemm(
    const float* __restrict__ X, const float* __restrict__ Wih,
    const float* __restrict__ bih, const float* __restrict__ bhh,
    unsigned short* __restrict__ U3)
{
    __shared__ unsigned short As[64 * 160];   // X rows (batch m)
    __shared__ unsigned short Bs[64 * 160];   // Wih rows (j)
    const int tid = threadIdx.x;
    const int m0 = (blockIdx.x >> 3) * 64, n0 = (blockIdx.x & 7) * 64;
    const int w = tid >> 6, l = tid & 63;
    const int lq = l >> 4, lr = l & 15;

    const f32x4 zv = {0.f, 0.f, 0.f, 0.f};
    f32x4 acc[2][2] = {{zv, zv}, {zv, zv}};   // [jt][mt]

    for (int kh = 0; kh < 2; ++kh) {
        const int kbase = kh * 160;
        __syncthreads();
        for (int i = tid; i < 64 * 40; i += 256) {
            const int r = i / 40, q = i - r * 40;
            const int kg = kbase + q * 4;
            unsigned int a0 = 0, a1 = 0, b0 = 0, b1 = 0;
            if (kg + 4 <= IN_DIM) {
                const float4 v = *reinterpret_cast<const float4*>(X + (size_t)(m0 + r) * IN_DIM + kg);
                a0 = (unsigned)f2bf(v.x) | ((unsigned)f2bf(v.y) << 16);
                a1 = (unsigned)f2bf(v.z) | ((unsigned)f2bf(v.w) << 16);
                const float4 u = *reinterpret_cast<const float4*>(Wih + (size_t)(n0 + r) * IN_DIM + kg);
                b0 = (unsigned)f2bf(u.x) | ((unsigned)f2bf(u.y) << 16);
                b1 = (unsigned)f2bf(u.z) | ((unsigned)f2bf(u.w) << 16);
            }
            int byte = r * 320 + q * 8; byte ^= ((r & 7) << 4);
            *reinterpret_cast<uint2*>(reinterpret_cast<char*>(As) + byte) = make_uint2(a0, a1);
            *reinterpret_cast<uint2*>(reinterpret_cast<char*>(Bs) + byte) = make_uint2(b0, b1);
        }
        __syncthreads();
        #pragma unroll
        for (int kc = 0; kc < 5; ++kc) {
            const int koff = kc * 64 + lq * 16;
            short8 xa[2], wb[2];
            #pragma unroll
            for (int mt = 0; mt < 2; ++mt) {
                const int row = (w >> 1) * 32 + mt * 16 + lr;       // X row (m)
                int abyte = row * 320 + koff; abyte ^= ((row & 7) << 4);
                xa[mt] = *reinterpret_cast<const short8*>(reinterpret_cast<const char*>(As) + abyte);
                const int jrow = (w & 1) * 32 + mt * 16 + lr;       // W row (j)
                int bbyte = jrow * 320 + koff; bbyte ^= ((jrow & 7) << 4);
                wb[mt] = *reinterpret_cast<const short8*>(reinterpret_cast<const char*>(Bs) + bbyte);
            }
            #pragma unroll
            for (int jt = 0; jt < 2; ++jt)
                #pragma unroll
                for (int mt = 0; mt < 2; ++mt)
                    acc[jt][mt] = __builtin_amdgcn_mfma_f32_16x16x32_bf16(
                        wb[jt], xa[mt], acc[jt][mt], 0, 0, 0);
        }
    }
    const int t = blockIdx.x >> 3;
    #pragma unroll
    for (int jt = 0; jt < 2; ++jt) {
        const int jb = n0 + (w & 1) * 32 + jt * 16 + 4 * lq;        // 4 consecutive j
        const float4 b1v = *reinterpret_cast<const float4*>(bih + jb);
        const float4 b2v = *reinterpret_cast<const float4*>(bhh + jb);
        const float4 bv = {b1v.x + b2v.x, b1v.y + b2v.y, b1v.z + b2v.z, b1v.w + b2v.w};
        const int jtg = jb >> 4;
        const int wv2 = jtg >> 2, cc = jtg & 3;
        #pragma unroll
        for (int mt = 0; mt < 2; ++mt) {
            const int b = (w >> 1) * 32 + mt * 16 + lr;             // batch row
            const int g = b >> 4, lrr = b & 15;
            const f32x4 a = acc[jt][mt];
            uint2 p;
            p.x = cvtpk(a[0] + bv.x, a[1] + bv.y);
            p.y = cvtpk(a[2] + bv.z, a[3] + bv.w);
            const size_t sidx = ((((size_t)t * 4 + g) * 8 + wv2) * 64 + (lq * 16 + lrr)) * 16 + cc * 4;
            *reinterpret_cast<uint2*>(U3 + sidx) = p;
        }
    }
}

// ---------------------------------------------------------------------------
// Kernel 2: int8 recurrence, zero inter-block traffic. 4 blocks x 512 thr.
// W_hh quantized per-row (j) to int8, ALL register-stationary: wq[4][8] =
// 128 regs/lane, static indices. h int8 (q=rint(127h)) in 2x8KB parity-
// double-buffered LDS (XOR-swizzled rows) -> 8 ds_read_b128/wave/step,
// 32 i8-MFMA (K=64)/wave/step, ONE barrier/step. Exact int32 accumulation,
// rescale by rowmax_j/127^2. U stays bf16 (f32 add).
// ---------------------------------------------------------------------------
__global__ __launch_bounds__(512) __attribute__((amdgpu_waves_per_eu(2, 2)))
void rnn_rec(const float* __restrict__ Whh, const unsigned short* __restrict__ U3,
             float* __restrict__ out)
{
    const int g = blockIdx.x;                // 0..3
    const int tid = threadIdx.x;
    const int w = tid >> 6, l = tid & 63;
    const int lq = l >> 4, lr = l & 15;

    __shared__ char h8[2 * 16 * 512];        // 16 KB, [parity][m][j] swizzled
    __shared__ float wsc_lds[512];           // per-j output scale

    // ---- one-time: load + quantize W to registers (static-indexed) ----
    // A-frag: lane holds W[j=(4w+c)*16+lr][k = kt*64 + lq*16 + e], e=0..15.
    i32x4 wq[4][8];
    float sc[4][4];
    #pragma unroll
    for (int c = 0; c < 4; ++c) {
        const float* wr = Whh + (size_t)((4 * w + c) * 16 + lr) * HID;
        float amax = 0.f;
        #pragma unroll
        for (int kt = 0; kt < 8; ++kt) {
            const int k0 = kt * 64 + lq * 16;
            #pragma unroll
            for (int q4 = 0; q4 < 4; ++q4) {
                const float4 v = *reinterpret_cast<const float4*>(wr + k0 + q4 * 4);
                amax = fmaxf(amax, fmaxf(fmaxf(fabsf(v.x), fabsf(v.y)),
                                         fmaxf(fabsf(v.z), fabsf(v.w))));
            }
        }
        amax = fmaxf(amax, __shfl_xor(amax, 16));
        amax = fmaxf(amax, __shfl_xor(amax, 32));    // full-row max
        const float inv = 127.f / amax;
        #pragma unroll
        for (int kt = 0; kt < 8; ++kt) {
            const int k0 = kt * 64 + lq * 16;
            i32x4 pk;
            #pragma unroll
            for (int q4 = 0; q4 < 4; ++q4) {
                const float4 v = *reinterpret_cast<const float4*>(wr + k0 + q4 * 4);
                const int q0 = (int)rintf(v.x * inv), q1 = (int)rintf(v.y * inv);
                const int q2 = (int)rintf(v.z * inv), q3 = (int)rintf(v.w * inv);
                pk[q4] = (q0 & 255) | ((q1 & 255) << 8) | ((q2 & 255) << 16) | (q3 << 24);
            }
            wq[c][kt] = pk;
        }
        if (lq == 0) wsc_lds[(4 * w + c) * 16 + lr] = amax / 16129.f;   // /127^2
    }
    // ---- h0 = 0 (both parities) ----
    for (int i = tid * 32; i < 2 * 16 * 512; i += 512 * 32) {
        *reinterpret_cast<uint4*>(h8 + i) = make_uint4(0, 0, 0, 0);
        *reinterpret_cast<uint4*>(h8 + i + 16) = make_uint4(0, 0, 0, 0);
    }
    __syncthreads();
    // D-column scales: lane owns j = (4w+c)*16 + 4lq + r
    #pragma unroll
    for (int c = 0; c < 4; ++c)
        #pragma unroll
        for (int r = 0; r < 4; ++r)
            sc[c][r] = wsc_lds[(4 * w + c) * 16 + 4 * lq + r];

    const unsigned short* uptr = U3 + ((size_t)(g * 8 + w) * 64 + l) * 16;
    const int swz = (lr & 7) << 4;
    const int rrow = lr * 512;
    const int wb0 = (4 * w) * 16 + 4 * lq;       // h-write col byte, c stride 16

    #pragma unroll 1
    for (int t = 0; t < T_STEPS; ++t) {
        const uint4 ua = *reinterpret_cast<const uint4*>(uptr);       // c=0,1
        const uint4 ub = *reinterpret_cast<const uint4*>(uptr + 8);   // c=2,3
        uptr += 32768;

        const char* hb = h8 + (t & 1) * 8192;
        i32x4 acc[4] = {{0,0,0,0}, {0,0,0,0}, {0,0,0,0}, {0,0,0,0}};
        #pragma unroll
        for (int kt = 0; kt < 8; ++kt) {
            const int cb = kt * 64 + lq * 16;
            const i32x4 hv = *reinterpret_cast<const i32x4*>(hb + rrow + (cb ^ swz));
            acc[0] = __builtin_amdgcn_mfma_i32_16x16x64_i8(wq[0][kt], hv, acc[0], 0, 0, 0);
            acc[1] = __builtin_amdgcn_mfma_i32_16x16x64_i8(wq[1][kt], hv, acc[1], 0, 0, 0);
            acc[2] = __builtin_amdgcn_mfma_i32_16x16x64_i8(wq[2][kt], hv, acc[2], 0, 0, 0);
            acc[3] = __builtin_amdgcn_mfma_i32_16x16x64_i8(wq[3][kt], hv, acc[3], 0, 0, 0);
        }

        // tanh( acc*sc + u ):  j = (4w+c)*16 + 4lq + r, m = lr
        float th[4][4];
        #pragma unroll
        for (int c = 0; c < 4; ++c) {
            const unsigned w0 = (c == 0) ? ua.x : (c == 1) ? ua.z : (c == 2) ? ub.x : ub.z;
            const unsigned w1 = (c == 0) ? ua.y : (c == 1) ? ua.w : (c == 2) ? ub.y : ub.w;
            #pragma unroll
            for (int r = 0; r < 4; ++r) {
                const unsigned word = (r < 2) ? w0 : w1;
                const float uf = __uint_as_float((r & 1) ? (word & 0xFFFF0000u) : (word << 16));
                const float x = fmaf((float)acc[c][r], sc[c][r], uf);
                const float e = __expf(2.f * x);
                th[c][r] = 1.f - __fdividef(2.f, e + 1.f);
            }
        }

        if (t == T_STEPS - 1) {
            #pragma unroll
            for (int c = 0; c < 4; ++c) {
                const float4 o = {th[c][0], th[c][1], th[c][2], th[c][3]};
                *reinterpret_cast<float4*>(out + (size_t)(g * 16 + lr) * HID +
                                           (4 * w + c) * 16 + 4 * lq) = o;
            }
            return;
        }

        // quantize h(t+1) -> int8, write to other parity buffer
        char* hw = h8 + ((t + 1) & 1) * 8192;
        #pragma unroll
        for (int c = 0; c < 4; ++c) {
            const int q0 = (int)rintf(th[c][0] * 127.f);
            const int q1 = (int)rintf(th[c][1] * 127.f);
            const int q2 = (int)rintf(th[c][2] * 127.f);
            const int q3 = (int)rintf(th[c][3] * 127.f);
            const unsigned pk = (q0 & 255) | ((q1 & 255) << 8) |
                                ((q2 & 255) << 16) | ((unsigned)q3 << 24);
            const int cb = wb0 + c * 16;
            *reinterpret_cast<unsigned*>(hw + rrow + (cb ^ swz)) = pk;
        }
        __syncthreads();   // h(t+1) visible; WAR safe (other parity)
    }
}

// ---------------------------------------------------------------------------
extern "C" void kernel_launch(void* const* d_in, const int* in_sizes, int n_in,
                              void* d_out, int out_size, void* d_ws, size_t ws_size,
                              hipStream_t stream) {
    const float* X   = (const float*)d_in[0];   // [2048][64][300]
    const float* Wih = (const float*)d_in[1];   // [512][300]
    const float* Whh = (const float*)d_in[2];   // [512][512]
    const float* bih = (const float*)d_in[3];   // [512]
    const float* bhh = (const float*)d_in[4];   // [512]
    float* out = (float*)d_out;                 // [64][512]
    unsigned short* U3 = (unsigned short*)d_ws; // 128 MB, rec-lane order

    u_gemm<<<dim3(2048 * 8), dim3(256), 0, stream>>>(X, Wih, bih, bhh, U3);
    rnn_rec<<<dim3(4), dim3(512), 0, stream>>>(Whh, U3, out);
}

// Round 6
// 2346.756 us; speedup vs baseline: 7.6803x; 1.7530x over previous
//
#include <hip/hip_runtime.h>
#include <hip/hip_bf16.h>

#define T_STEPS 2048
#define NB      64
#define IN_DIM  300
#define HID     512

typedef __attribute__((ext_vector_type(8))) short short8;   // 8 bf16 (4 VGPR)
typedef __attribute__((ext_vector_type(4))) float f32x4;    // MFMA f32 accum
typedef __attribute__((ext_vector_type(4))) int   i32x4;    // MFMA i8 frag/accum

#define SCALE2LOG2E 2.8853900817779268f   // 2*log2(e): exp(2x) = 2^(x*SCALE2LOG2E)

static __device__ __forceinline__ unsigned short f2bf(float x) {
    unsigned int u = __float_as_uint(x);
    u = u + 0x7FFFu + ((u >> 16) & 1u);          // round-to-nearest-even
    return (unsigned short)(u >> 16);
}
static __device__ __forceinline__ unsigned cvtpk(float lo, float hi) {
    unsigned r;
    asm("v_cvt_pk_bf16_f32 %0, %1, %2" : "=v"(r) : "v"(lo), "v"(hi));
    return r;
}
static __device__ __forceinline__ float fexp2(float x) {
    float r; asm("v_exp_f32 %0, %1" : "=v"(r) : "v"(x)); return r;
}
static __device__ __forceinline__ float frcp(float x) {
    float r; asm("v_rcp_f32 %0, %1" : "=v"(r) : "v"(x)); return r;
}
// v_perm_b32: D bytes select from {S0(hi):S1(lo)}; sel byte 0-3 -> S1, 4-7 -> S0
static __device__ __forceinline__ unsigned vperm(unsigned hi, unsigned lo, unsigned sel) {
    unsigned d;
    asm("v_perm_b32 %0, %1, %2, %3" : "=v"(d) : "v"(hi), "v"(lo), "s"(sel));
    return d;
}

// tanh+int8-quantize 4 values: x2 = cvt(acc)*sc + u2 (all pre-scaled by 2log2e)
// th = 1 - 2/(2^x2 + 1);  q = RNE(127*th) via add-magic; pack 4 bytes via v_perm.
static __device__ __forceinline__ unsigned tq4(const i32x4 a, const f32x4 s,
                                               unsigned w0, unsigned w1) {
    unsigned q[4];
    #pragma unroll
    for (int r = 0; r < 4; ++r) {
        const unsigned word = (r < 2) ? w0 : w1;
        const float uf = __uint_as_float((r & 1) ? (word & 0xFFFF0000u) : (word << 16));
        const float x2 = fmaf((float)a[r], s[r], uf);
        const float d = fexp2(x2) + 1.f;
        // 12583039 = 2^23 + 2^22 + 127; qf = magic + (127 - 254*rcp) -> byte0 = int8
        q[r] = __float_as_uint(fmaf(frcp(d), -254.f, 12583039.f));
    }
    return vperm(vperm(q[3], q[2], 0x0C0C0400u),
                 vperm(q[1], q[0], 0x0C0C0400u), 0x05040100u);
}

// ---------------------------------------------------------------------------
// Kernel 1: U = bf16( (x_t W_ih^T + b_ih + b_hh) * 2log2e ), rec-lane order:
// U3[t][g(4)][w(8)][lane(64)][c(4)][r(4)]  (value = pre[b=g*16+lr][j=(4w+c)*16+4lq+r])
// ---------------------------------------------------------------------------
__global__ __launch_bounds__(256, 4) void u_gemm(
    const float* __restrict__ X, const float* __restrict__ Wih,
    const float* __restrict__ bih, const float* __restrict__ bhh,
    unsigned short* __restrict__ U3)
{
    __shared__ unsigned short As[64 * 160];   // X rows (batch m)
    __shared__ unsigned short Bs[64 * 160];   // Wih rows (j)
    const int tid = threadIdx.x;
    const int m0 = (blockIdx.x >> 3) * 64, n0 = (blockIdx.x & 7) * 64;
    const int w = tid >> 6, l = tid & 63;
    const int lq = l >> 4, lr = l & 15;

    const f32x4 zv = {0.f, 0.f, 0.f, 0.f};
    f32x4 acc[2][2] = {{zv, zv}, {zv, zv}};   // [jt][mt]

    for (int kh = 0; kh < 2; ++kh) {
        const int kbase = kh * 160;
        __syncthreads();
        for (int i = tid; i < 64 * 40; i += 256) {
            const int r = i / 40, q = i - r * 40;
            const int kg = kbase + q * 4;
            unsigned int a0 = 0, a1 = 0, b0 = 0, b1 = 0;
            if (kg + 4 <= IN_DIM) {
                const float4 v = *reinterpret_cast<const float4*>(X + (size_t)(m0 + r) * IN_DIM + kg);
                a0 = (unsigned)f2bf(v.x) | ((unsigned)f2bf(v.y) << 16);
                a1 = (unsigned)f2bf(v.z) | ((unsigned)f2bf(v.w) << 16);
                const float4 u = *reinterpret_cast<const float4*>(Wih + (size_t)(n0 + r) * IN_DIM + kg);
                b0 = (unsigned)f2bf(u.x) | ((unsigned)f2bf(u.y) << 16);
                b1 = (unsigned)f2bf(u.z) | ((unsigned)f2bf(u.w) << 16);
            }
            int byte = r * 320 + q * 8; byte ^= ((r & 7) << 4);
            *reinterpret_cast<uint2*>(reinterpret_cast<char*>(As) + byte) = make_uint2(a0, a1);
            *reinterpret_cast<uint2*>(reinterpret_cast<char*>(Bs) + byte) = make_uint2(b0, b1);
        }
        __syncthreads();
        #pragma unroll
        for (int kc = 0; kc < 5; ++kc) {
            const int koff = kc * 64 + lq * 16;
            short8 xa[2], wb[2];
            #pragma unroll
            for (int mt = 0; mt < 2; ++mt) {
                const int row = (w >> 1) * 32 + mt * 16 + lr;       // X row (m)
                int abyte = row * 320 + koff; abyte ^= ((row & 7) << 4);
                xa[mt] = *reinterpret_cast<const short8*>(reinterpret_cast<const char*>(As) + abyte);
                const int jrow = (w & 1) * 32 + mt * 16 + lr;       // W row (j)
                int bbyte = jrow * 320 + koff; bbyte ^= ((jrow & 7) << 4);
                wb[mt] = *reinterpret_cast<const short8*>(reinterpret_cast<const char*>(Bs) + bbyte);
            }
            #pragma unroll
            for (int jt = 0; jt < 2; ++jt)
                #pragma unroll
                for (int mt = 0; mt < 2; ++mt)
                    acc[jt][mt] = __builtin_amdgcn_mfma_f32_16x16x32_bf16(
                        wb[jt], xa[mt], acc[jt][mt], 0, 0, 0);
        }
    }
    const int t = blockIdx.x >> 3;
    #pragma unroll
    for (int jt = 0; jt < 2; ++jt) {
        const int jb = n0 + (w & 1) * 32 + jt * 16 + 4 * lq;        // 4 consecutive j
        const float4 b1v = *reinterpret_cast<const float4*>(bih + jb);
        const float4 b2v = *reinterpret_cast<const float4*>(bhh + jb);
        const float4 bv = {(b1v.x + b2v.x) * SCALE2LOG2E, (b1v.y + b2v.y) * SCALE2LOG2E,
                           (b1v.z + b2v.z) * SCALE2LOG2E, (b1v.w + b2v.w) * SCALE2LOG2E};
        const int jtg = jb >> 4;
        const int wv2 = jtg >> 2, cc = jtg & 3;
        #pragma unroll
        for (int mt = 0; mt < 2; ++mt) {
            const int b = (w >> 1) * 32 + mt * 16 + lr;             // batch row
            const int g = b >> 4, lrr = b & 15;
            const f32x4 a = acc[jt][mt];
            uint2 p;
            p.x = cvtpk(fmaf(a[0], SCALE2LOG2E, bv.x), fmaf(a[1], SCALE2LOG2E, bv.y));
            p.y = cvtpk(fmaf(a[2], SCALE2LOG2E, bv.z), fmaf(a[3], SCALE2LOG2E, bv.w));
            const size_t sidx = ((((size_t)t * 4 + g) * 8 + wv2) * 64 + (lq * 16 + lrr)) * 16 + cc * 4;
            *reinterpret_cast<uint2*>(U3 + sidx) = p;
        }
    }
}

// ---------------------------------------------------------------------------
// Kernel 2: int8 recurrence. 4 blocks x 512 thr, W register-stationary
// (wq[4][8], static idx), h int8 in 2x8KB parity LDS, 1 barrier/step.
// 2-pass MFMA (c01 then c23) so tanh(c01) overlaps pass-2 matrix work.
// tanh+quant: 4 VALU + 2 trans per value via exp2 identity + add-magic int8.
// U prefetched one step ahead (ping-pong regs, 2-step unrolled loop).
// ---------------------------------------------------------------------------
__global__ __launch_bounds__(512) __attribute__((amdgpu_waves_per_eu(2, 2)))
void rnn_rec(const float* __restrict__ Whh, const unsigned short* __restrict__ U3,
             float* __restrict__ out)
{
    const int g = blockIdx.x;                // 0..3
    const int tid = threadIdx.x;
    const int w = tid >> 6, l = tid & 63;
    const int lq = l >> 4, lr = l & 15;

    __shared__ char h8[2 * 16 * 512];        // [parity][m][k] swizzled
    __shared__ float wsc_lds[512];           // per-j scale (pre-scaled by 2log2e)

    // ---- one-time: quantize W to registers (static-indexed) ----
    i32x4 wq[4][8];
    #pragma unroll
    for (int c = 0; c < 4; ++c) {
        const float* wr = Whh + (size_t)((4 * w + c) * 16 + lr) * HID;
        float amax = 0.f;
        #pragma unroll
        for (int kt = 0; kt < 8; ++kt) {
            const int k0 = kt * 64 + lq * 16;
            #pragma unroll
            for (int q4 = 0; q4 < 4; ++q4) {
                const float4 v = *reinterpret_cast<const float4*>(wr + k0 + q4 * 4);
                amax = fmaxf(amax, fmaxf(fmaxf(fabsf(v.x), fabsf(v.y)),
                                         fmaxf(fabsf(v.z), fabsf(v.w))));
            }
        }
        amax = fmaxf(amax, __shfl_xor(amax, 16));
        amax = fmaxf(amax, __shfl_xor(amax, 32));    // full-row max
        const float inv = 127.f / amax;
        #pragma unroll
        for (int kt = 0; kt < 8; ++kt) {
            const int k0 = kt * 64 + lq * 16;
            i32x4 pk;
            #pragma unroll
            for (int q4 = 0; q4 < 4; ++q4) {
                const float4 v = *reinterpret_cast<const float4*>(wr + k0 + q4 * 4);
                const int q0 = (int)rintf(v.x * inv), q1 = (int)rintf(v.y * inv);
                const int q2 = (int)rintf(v.z * inv), q3 = (int)rintf(v.w * inv);
                pk[q4] = (q0 & 255) | ((q1 & 255) << 8) | ((q2 & 255) << 16) | (q3 << 24);
            }
            wq[c][kt] = pk;
        }
        if (lq == 0)
            wsc_lds[(4 * w + c) * 16 + lr] = amax * (SCALE2LOG2E / 16129.f);
    }
    // ---- h0 = 0 (both parities) ----
    for (int i = tid * 32; i < 2 * 16 * 512; i += 512 * 32) {
        *reinterpret_cast<uint4*>(h8 + i) = make_uint4(0, 0, 0, 0);
        *reinterpret_cast<uint4*>(h8 + i + 16) = make_uint4(0, 0, 0, 0);
    }
    __syncthreads();

    // per-lane D-column scales: j = (4w+c)*16 + 4lq + r
    f32x4 sc2[4];
    #pragma unroll
    for (int c = 0; c < 4; ++c) {
        const float4 s = *reinterpret_cast<const float4*>(&wsc_lds[(4 * w + c) * 16 + 4 * lq]);
        sc2[c] = f32x4{s.x, s.y, s.z, s.w};
    }

    const int swz = (lr & 7) << 4;
    const int rrow = lr * 512;
    const int lq16 = lq * 16;
    int wrA[4];
    #pragma unroll
    for (int c = 0; c < 4; ++c)
        wrA[c] = rrow + ((((4 * w + c) * 16) + 4 * lq) ^ swz);

    const unsigned short* ub = U3 + ((size_t)(g * 8 + w) * 64 + l) * 16;
    uint4 uA0 = *reinterpret_cast<const uint4*>(ub);
    uint4 uB0 = *reinterpret_cast<const uint4*>(ub + 8);
    const unsigned short* uptr = ub + 32768;
    uint4 uA1, uB1;

#define RSTEP(T_, UA, UB, UAN, UBN)                                            \
    {                                                                          \
        UAN = *reinterpret_cast<const uint4*>(uptr);                           \
        UBN = *reinterpret_cast<const uint4*>(uptr + 8);                       \
        uptr += 32768;                                                         \
        const char* hb_ = h8 + ((T_) & 1) * 8192;                              \
        i32x4 a0 = {0,0,0,0}, a1 = {0,0,0,0}, a2 = {0,0,0,0}, a3 = {0,0,0,0};  \
        _Pragma("unroll")                                                      \
        for (int kt = 0; kt < 8; ++kt) {                                       \
            const i32x4 hv = *reinterpret_cast<const i32x4*>(                  \
                hb_ + rrow + ((kt * 64 + lq16) ^ swz));                        \
            a0 = __builtin_amdgcn_mfma_i32_16x16x64_i8(wq[0][kt], hv, a0, 0, 0, 0); \
            a1 = __builtin_amdgcn_mfma_i32_16x16x64_i8(wq[1][kt], hv, a1, 0, 0, 0); \
        }                                                                      \
        _Pragma("unroll")                                                      \
        for (int kt = 0; kt < 8; ++kt) {                                       \
            const i32x4 hv = *reinterpret_cast<const i32x4*>(                  \
                hb_ + rrow + ((kt * 64 + lq16) ^ swz));                        \
            a2 = __builtin_amdgcn_mfma_i32_16x16x64_i8(wq[2][kt], hv, a2, 0, 0, 0); \
            a3 = __builtin_amdgcn_mfma_i32_16x16x64_i8(wq[3][kt], hv, a3, 0, 0, 0); \
        }                                                                      \
        char* hw_ = h8 + (((T_) + 1) & 1) * 8192;                              \
        *reinterpret_cast<unsigned*>(hw_ + wrA[0]) = tq4(a0, sc2[0], UA.x, UA.y); \
        *reinterpret_cast<unsigned*>(hw_ + wrA[1]) = tq4(a1, sc2[1], UA.z, UA.w); \
        *reinterpret_cast<unsigned*>(hw_ + wrA[2]) = tq4(a2, sc2[2], UB.x, UB.y); \
        *reinterpret_cast<unsigned*>(hw_ + wrA[3]) = tq4(a3, sc2[3], UB.z, UB.w); \
        __syncthreads();                                                       \
    }

    #pragma unroll 1
    for (int t = 0; t < T_STEPS - 2; t += 2) {
        RSTEP(t, uA0, uB0, uA1, uB1)
        RSTEP(t + 1, uA1, uB1, uA0, uB0)
    }
    // t = 2046 (prefetches t=2047 into uA1/uB1; uptr stays in-bounds)
    {
        uptr -= 32768;   // re-point: loop consumed through 2046 already
        uptr += 32768;
    }
    RSTEP(T_STEPS - 2, uA0, uB0, uA1, uB1)

    // ---- epilogue t = 2047: precise tanh, f32 store ----
    {
        const char* hb_ = h8 + ((T_STEPS - 1) & 1) * 8192;
        i32x4 a[4] = {{0,0,0,0}, {0,0,0,0}, {0,0,0,0}, {0,0,0,0}};
        #pragma unroll
        for (int kt = 0; kt < 8; ++kt) {
            const i32x4 hv = *reinterpret_cast<const i32x4*>(
                hb_ + rrow + ((kt * 64 + lq16) ^ swz));
            a[0] = __builtin_amdgcn_mfma_i32_16x16x64_i8(wq[0][kt], hv, a[0], 0, 0, 0);
            a[1] = __builtin_amdgcn_mfma_i32_16x16x64_i8(wq[1][kt], hv, a[1], 0, 0, 0);
            a[2] = __builtin_amdgcn_mfma_i32_16x16x64_i8(wq[2][kt], hv, a[2], 0, 0, 0);
            a[3] = __builtin_amdgcn_mfma_i32_16x16x64_i8(wq[3][kt], hv, a[3], 0, 0, 0);
        }
        #pragma unroll
        for (int c = 0; c < 4; ++c) {
            const unsigned w0 = (c == 0) ? uA1.x : (c == 1) ? uA1.z : (c == 2) ? uB1.x : uB1.z;
            const unsigned w1 = (c == 0) ? uA1.y : (c == 1) ? uA1.w : (c == 2) ? uB1.y : uB1.w;
            float th[4];
            #pragma unroll
            for (int r = 0; r < 4; ++r) {
                const unsigned word = (r < 2) ? w0 : w1;
                const float uf = __uint_as_float((r & 1) ? (word & 0xFFFF0000u) : (word << 16));
                const float x2 = fmaf((float)a[c][r], sc2[c][r], uf);
                const float d = fexp2(x2) + 1.f;
                th[r] = fmaf(frcp(d), -2.f, 1.f);
            }
            const float4 o = {th[0], th[1], th[2], th[3]};
            *reinterpret_cast<float4*>(out + (size_t)(g * 16 + lr) * HID +
                                       (4 * w + c) * 16 + 4 * lq) = o;
        }
    }
#undef RSTEP
}

// ---------------------------------------------------------------------------
extern "C" void kernel_launch(void* const* d_in, const int* in_sizes, int n_in,
                              void* d_out, int out_size, void* d_ws, size_t ws_size,
                              hipStream_t stream) {
    const float* X   = (const float*)d_in[0];   // [2048][64][300]
    const float* Wih = (const float*)d_in[1];   // [512][300]
    const float* Whh = (const float*)d_in[2];   // [512][512]
    const float* bih = (const float*)d_in[3];   // [512]
    const float* bhh = (const float*)d_in[4];   // [512]
    float* out = (float*)d_out;                 // [64][512]
    unsigned short* U3 = (unsigned short*)d_ws; // 128 MB, rec-lane order

    u_gemm<<<dim3(2048 * 8), dim3(256), 0, stream>>>(X, Wih, bih, bhh, U3);
    rnn_rec<<<dim3(4), dim3(512), 0, stream>>>(Whh, U3, out);
}

// Round 7
// 2337.026 us; speedup vs baseline: 7.7122x; 1.0042x over previous
//
#include <hip/hip_runtime.h>
#include <hip/hip_bf16.h>

#define T_STEPS 2048
#define NB      64
#define IN_DIM  300
#define HID     512

typedef __attribute__((ext_vector_type(8))) short short8;   // 8 bf16 (4 VGPR)
typedef __attribute__((ext_vector_type(4))) float f32x4;    // MFMA f32 accum
typedef __attribute__((ext_vector_type(4))) int   i32x4;    // MFMA i8 frag/accum

#define SCALE2LOG2E 2.8853900817779268f   // 2*log2(e): exp(2x) = 2^(x*SCALE2LOG2E)

static __device__ __forceinline__ unsigned short f2bf(float x) {
    unsigned int u = __float_as_uint(x);
    u = u + 0x7FFFu + ((u >> 16) & 1u);          // round-to-nearest-even
    return (unsigned short)(u >> 16);
}
static __device__ __forceinline__ unsigned cvtpk(float lo, float hi) {
    unsigned r;
    asm("v_cvt_pk_bf16_f32 %0, %1, %2" : "=v"(r) : "v"(lo), "v"(hi));
    return r;
}
static __device__ __forceinline__ float fexp2(float x) {
    float r; asm("v_exp_f32 %0, %1" : "=v"(r) : "v"(x)); return r;
}
static __device__ __forceinline__ float frcp(float x) {
    float r; asm("v_rcp_f32 %0, %1" : "=v"(r) : "v"(x)); return r;
}
static __device__ __forceinline__ unsigned vperm(unsigned hi, unsigned lo, unsigned sel) {
    unsigned d;
    asm("v_perm_b32 %0, %1, %2, %3" : "=v"(d) : "v"(hi), "v"(lo), "s"(sel));
    return d;
}

// tanh+int8-quantize 4 values: x2 = cvt(acc)*sc + u2 (pre-scaled by 2log2e)
// th = 1 - 2/(2^x2+1);  q = RNE(127*th) via add-magic; pack via v_perm.
static __device__ __forceinline__ unsigned tq4(const i32x4 a, const f32x4 s,
                                               unsigned w0, unsigned w1) {
    unsigned q[4];
    #pragma unroll
    for (int r = 0; r < 4; ++r) {
        const unsigned word = (r < 2) ? w0 : w1;
        const float uf = __uint_as_float((r & 1) ? (word & 0xFFFF0000u) : (word << 16));
        const float x2 = fmaf((float)a[r], s[r], uf);
        const float d = fexp2(x2) + 1.f;
        q[r] = __float_as_uint(fmaf(frcp(d), -254.f, 12583039.f));   // byte0 = int8
    }
    return vperm(vperm(q[3], q[2], 0x0C0C0400u),
                 vperm(q[1], q[0], 0x0C0C0400u), 0x05040100u);
}

// ---------------------------------------------------------------------------
// Kernel 1: U = bf16( (x_t W_ih^T + b_ih + b_hh) * 2log2e ), rec-lane order:
// U3[t][g(4)][w(8)][lane(64)][c(4)][r(4)]  (value = pre[b=g*16+lr][j=(4w+c)*16+4lq+r])
// ---------------------------------------------------------------------------
__global__ __launch_bounds__(256, 4) void u_gemm(
    const float* __restrict__ X, const float* __restrict__ Wih,
    const float* __restrict__ bih, const float* __restrict__ bhh,
    unsigned short* __restrict__ U3)
{
    __shared__ unsigned short As[64 * 160];   // X rows (batch m)
    __shared__ unsigned short Bs[64 * 160];   // Wih rows (j)
    const int tid = threadIdx.x;
    const int m0 = (blockIdx.x >> 3) * 64, n0 = (blockIdx.x & 7) * 64;
    const int w = tid >> 6, l = tid & 63;
    const int lq = l >> 4, lr = l & 15;

    const f32x4 zv = {0.f, 0.f, 0.f, 0.f};
    f32x4 acc[2][2] = {{zv, zv}, {zv, zv}};   // [jt][mt]

    for (int kh = 0; kh < 2; ++kh) {
        const int kbase = kh * 160;
        __syncthreads();
        for (int i = tid; i < 64 * 40; i += 256) {
            const int r = i / 40, q = i - r * 40;
            const int kg = kbase + q * 4;
            unsigned int a0 = 0, a1 = 0, b0 = 0, b1 = 0;
            if (kg + 4 <= IN_DIM) {
                const float4 v = *reinterpret_cast<const float4*>(X + (size_t)(m0 + r) * IN_DIM + kg);
                a0 = (unsigned)f2bf(v.x) | ((unsigned)f2bf(v.y) << 16);
                a1 = (unsigned)f2bf(v.z) | ((unsigned)f2bf(v.w) << 16);
                const float4 u = *reinterpret_cast<const float4*>(Wih + (size_t)(n0 + r) * IN_DIM + kg);
                b0 = (unsigned)f2bf(u.x) | ((unsigned)f2bf(u.y) << 16);
                b1 = (unsigned)f2bf(u.z) | ((unsigned)f2bf(u.w) << 16);
            }
            int byte = r * 320 + q * 8; byte ^= ((r & 7) << 4);
            *reinterpret_cast<uint2*>(reinterpret_cast<char*>(As) + byte) = make_uint2(a0, a1);
            *reinterpret_cast<uint2*>(reinterpret_cast<char*>(Bs) + byte) = make_uint2(b0, b1);
        }
        __syncthreads();
        #pragma unroll
        for (int kc = 0; kc < 5; ++kc) {
            const int koff = kc * 64 + lq * 16;
            short8 xa[2], wb[2];
            #pragma unroll
            for (int mt = 0; mt < 2; ++mt) {
                const int row = (w >> 1) * 32 + mt * 16 + lr;       // X row (m)
                int abyte = row * 320 + koff; abyte ^= ((row & 7) << 4);
                xa[mt] = *reinterpret_cast<const short8*>(reinterpret_cast<const char*>(As) + abyte);
                const int jrow = (w & 1) * 32 + mt * 16 + lr;       // W row (j)
                int bbyte = jrow * 320 + koff; bbyte ^= ((jrow & 7) << 4);
                wb[mt] = *reinterpret_cast<const short8*>(reinterpret_cast<const char*>(Bs) + bbyte);
            }
            #pragma unroll
            for (int jt = 0; jt < 2; ++jt)
                #pragma unroll
                for (int mt = 0; mt < 2; ++mt)
                    acc[jt][mt] = __builtin_amdgcn_mfma_f32_16x16x32_bf16(
                        wb[jt], xa[mt], acc[jt][mt], 0, 0, 0);
        }
    }
    const int t = blockIdx.x >> 3;
    #pragma unroll
    for (int jt = 0; jt < 2; ++jt) {
        const int jb = n0 + (w & 1) * 32 + jt * 16 + 4 * lq;        // 4 consecutive j
        const float4 b1v = *reinterpret_cast<const float4*>(bih + jb);
        const float4 b2v = *reinterpret_cast<const float4*>(bhh + jb);
        const float4 bv = {(b1v.x + b2v.x) * SCALE2LOG2E, (b1v.y + b2v.y) * SCALE2LOG2E,
                           (b1v.z + b2v.z) * SCALE2LOG2E, (b1v.w + b2v.w) * SCALE2LOG2E};
        const int jtg = jb >> 4;
        const int wv2 = jtg >> 2, cc = jtg & 3;
        #pragma unroll
        for (int mt = 0; mt < 2; ++mt) {
            const int b = (w >> 1) * 32 + mt * 16 + lr;             // batch row
            const int g = b >> 4, lrr = b & 15;
            const f32x4 a = acc[jt][mt];
            uint2 p;
            p.x = cvtpk(fmaf(a[0], SCALE2LOG2E, bv.x), fmaf(a[1], SCALE2LOG2E, bv.y));
            p.y = cvtpk(fmaf(a[2], SCALE2LOG2E, bv.z), fmaf(a[3], SCALE2LOG2E, bv.w));
            const size_t sidx = ((((size_t)t * 4 + g) * 8 + wv2) * 64 + (lq * 16 + lrr)) * 16 + cc * 4;
            *reinterpret_cast<uint2*>(U3 + sidx) = p;
        }
    }
}

// ---------------------------------------------------------------------------
// Kernel 2: int8 recurrence. 4 blocks x 512 thr. W register-stationary
// (wq[4][8], static idx). Per step: 8 ds_read_b128 -> hv[8] regs (read ONCE),
// 32 MFMA; tq4(a0)/tq4(a1)+stores source-interleaved between a2/a3 MFMA pairs
// so per-wave VALU fills matrix-pipe gaps (in-order issue). 1 barrier/step.
// ---------------------------------------------------------------------------
__global__ __launch_bounds__(512) __attribute__((amdgpu_waves_per_eu(2, 2)))
void rnn_rec(const float* __restrict__ Whh, const unsigned short* __restrict__ U3,
             float* __restrict__ out)
{
    const int g = blockIdx.x;                // 0..3
    const int tid = threadIdx.x;
    const int w = tid >> 6, l = tid & 63;
    const int lq = l >> 4, lr = l & 15;

    __shared__ char h8[2 * 16 * 512];        // [parity][m][k] swizzled
    __shared__ float wsc_lds[512];           // per-j scale (pre-scaled by 2log2e)

    // ---- one-time: quantize W to registers (static-indexed) ----
    i32x4 wq[4][8];
    #pragma unroll
    for (int c = 0; c < 4; ++c) {
        const float* wr = Whh + (size_t)((4 * w + c) * 16 + lr) * HID;
        float amax = 0.f;
        #pragma unroll
        for (int kt = 0; kt < 8; ++kt) {
            const int k0 = kt * 64 + lq * 16;
            #pragma unroll
            for (int q4 = 0; q4 < 4; ++q4) {
                const float4 v = *reinterpret_cast<const float4*>(wr + k0 + q4 * 4);
                amax = fmaxf(amax, fmaxf(fmaxf(fabsf(v.x), fabsf(v.y)),
                                         fmaxf(fabsf(v.z), fabsf(v.w))));
            }
        }
        amax = fmaxf(amax, __shfl_xor(amax, 16));
        amax = fmaxf(amax, __shfl_xor(amax, 32));    // full-row max
        const float inv = 127.f / amax;
        #pragma unroll
        for (int kt = 0; kt < 8; ++kt) {
            const int k0 = kt * 64 + lq * 16;
            i32x4 pk;
            #pragma unroll
            for (int q4 = 0; q4 < 4; ++q4) {
                const float4 v = *reinterpret_cast<const float4*>(wr + k0 + q4 * 4);
                const int q0 = (int)rintf(v.x * inv), q1 = (int)rintf(v.y * inv);
                const int q2 = (int)rintf(v.z * inv), q3 = (int)rintf(v.w * inv);
                pk[q4] = (q0 & 255) | ((q1 & 255) << 8) | ((q2 & 255) << 16) | (q3 << 24);
            }
            wq[c][kt] = pk;
        }
        if (lq == 0)
            wsc_lds[(4 * w + c) * 16 + lr] = amax * (SCALE2LOG2E / 16129.f);
    }
    // ---- h0 = 0 (both parities) ----
    for (int i = tid * 32; i < 2 * 16 * 512; i += 512 * 32) {
        *reinterpret_cast<uint4*>(h8 + i) = make_uint4(0, 0, 0, 0);
        *reinterpret_cast<uint4*>(h8 + i + 16) = make_uint4(0, 0, 0, 0);
    }
    __syncthreads();

    // per-lane D-column scales: j = (4w+c)*16 + 4lq + r
    f32x4 sc2[4];
    #pragma unroll
    for (int c = 0; c < 4; ++c) {
        const float4 s = *reinterpret_cast<const float4*>(&wsc_lds[(4 * w + c) * 16 + 4 * lq]);
        sc2[c] = f32x4{s.x, s.y, s.z, s.w};
    }

    const int swz = (lr & 7) << 4;
    const int rrow = lr * 512;
    const int lq16 = lq * 16;
    int wrA[4];
    #pragma unroll
    for (int c = 0; c < 4; ++c)
        wrA[c] = rrow + ((((4 * w + c) * 16) + 4 * lq) ^ swz);

    const unsigned short* ub = U3 + ((size_t)(g * 8 + w) * 64 + l) * 16;
    uint4 uA0 = *reinterpret_cast<const uint4*>(ub);
    uint4 uB0 = *reinterpret_cast<const uint4*>(ub + 8);
    const unsigned short* uptr = ub + 32768;
    uint4 uA1, uB1;

#define MFMA_I8(W_, H_, A_) __builtin_amdgcn_mfma_i32_16x16x64_i8(W_, H_, A_, 0, 0, 0)

#define RSTEP(T_, UA, UB, UAN, UBN)                                            \
    {                                                                          \
        UAN = *reinterpret_cast<const uint4*>(uptr);                           \
        UBN = *reinterpret_cast<const uint4*>(uptr + 8);                       \
        uptr += 32768;                                                         \
        const char* hb_ = h8 + ((T_) & 1) * 8192;                              \
        char* hw_ = h8 + (((T_) + 1) & 1) * 8192;                              \
        i32x4 hv[8];                                                           \
        _Pragma("unroll")                                                      \
        for (int kt = 0; kt < 8; ++kt)                                         \
            hv[kt] = *reinterpret_cast<const i32x4*>(                          \
                hb_ + rrow + ((kt * 64 + lq16) ^ swz));                        \
        i32x4 a0 = {0,0,0,0}, a1 = {0,0,0,0}, a2 = {0,0,0,0}, a3 = {0,0,0,0};  \
        _Pragma("unroll")                                                      \
        for (int kt = 0; kt < 8; ++kt) {                                       \
            a0 = MFMA_I8(wq[0][kt], hv[kt], a0);                               \
            a1 = MFMA_I8(wq[1][kt], hv[kt], a1);                               \
        }                                                                      \
        a2 = MFMA_I8(wq[2][0], hv[0], a2);  a3 = MFMA_I8(wq[3][0], hv[0], a3); \
        a2 = MFMA_I8(wq[2][1], hv[1], a2);  a3 = MFMA_I8(wq[3][1], hv[1], a3); \
        const unsigned q0 = tq4(a0, sc2[0], UA.x, UA.y);                       \
        a2 = MFMA_I8(wq[2][2], hv[2], a2);  a3 = MFMA_I8(wq[3][2], hv[2], a3); \
        a2 = MFMA_I8(wq[2][3], hv[3], a2);  a3 = MFMA_I8(wq[3][3], hv[3], a3); \
        const unsigned q1 = tq4(a1, sc2[1], UA.z, UA.w);                       \
        a2 = MFMA_I8(wq[2][4], hv[4], a2);  a3 = MFMA_I8(wq[3][4], hv[4], a3); \
        a2 = MFMA_I8(wq[2][5], hv[5], a2);  a3 = MFMA_I8(wq[3][5], hv[5], a3); \
        *reinterpret_cast<unsigned*>(hw_ + wrA[0]) = q0;                       \
        *reinterpret_cast<unsigned*>(hw_ + wrA[1]) = q1;                       \
        a2 = MFMA_I8(wq[2][6], hv[6], a2);  a3 = MFMA_I8(wq[3][6], hv[6], a3); \
        a2 = MFMA_I8(wq[2][7], hv[7], a2);  a3 = MFMA_I8(wq[3][7], hv[7], a3); \
        *reinterpret_cast<unsigned*>(hw_ + wrA[2]) = tq4(a2, sc2[2], UB.x, UB.y); \
        *reinterpret_cast<unsigned*>(hw_ + wrA[3]) = tq4(a3, sc2[3], UB.z, UB.w); \
        __syncthreads();                                                       \
    }

    #pragma unroll 1
    for (int t = 0; t < T_STEPS - 2; t += 2) {
        RSTEP(t, uA0, uB0, uA1, uB1)
        RSTEP(t + 1, uA1, uB1, uA0, uB0)
    }
    RSTEP(T_STEPS - 2, uA0, uB0, uA1, uB1)

    // ---- epilogue t = 2047: precise tanh, f32 store ----
    {
        const char* hb_ = h8 + ((T_STEPS - 1) & 1) * 8192;
        i32x4 a[4] = {{0,0,0,0}, {0,0,0,0}, {0,0,0,0}, {0,0,0,0}};
        #pragma unroll
        for (int kt = 0; kt < 8; ++kt) {
            const i32x4 hv = *reinterpret_cast<const i32x4*>(
                hb_ + rrow + ((kt * 64 + lq16) ^ swz));
            a[0] = MFMA_I8(wq[0][kt], hv, a[0]);
            a[1] = MFMA_I8(wq[1][kt], hv, a[1]);
            a[2] = MFMA_I8(wq[2][kt], hv, a[2]);
            a[3] = MFMA_I8(wq[3][kt], hv, a[3]);
        }
        #pragma unroll
        for (int c = 0; c < 4; ++c) {
            const unsigned w0 = (c == 0) ? uA1.x : (c == 1) ? uA1.z : (c == 2) ? uB1.x : uB1.z;
            const unsigned w1 = (c == 0) ? uA1.y : (c == 1) ? uA1.w : (c == 2) ? uB1.y : uB1.w;
            float th[4];
            #pragma unroll
            for (int r = 0; r < 4; ++r) {
                const unsigned word = (r < 2) ? w0 : w1;
                const float uf = __uint_as_float((r & 1) ? (word & 0xFFFF0000u) : (word << 16));
                const float x2 = fmaf((float)a[c][r], sc2[c][r], uf);
                const float d = fexp2(x2) + 1.f;
                th[r] = fmaf(frcp(d), -2.f, 1.f);
            }
            const float4 o = {th[0], th[1], th[2], th[3]};
            *reinterpret_cast<float4*>(out + (size_t)(g * 16 + lr) * HID +
                                       (4 * w + c) * 16 + 4 * lq) = o;
        }
    }
#undef RSTEP
#undef MFMA_I8
}

// ---------------------------------------------------------------------------
extern "C" void kernel_launch(void* const* d_in, const int* in_sizes, int n_in,
                              void* d_out, int out_size, void* d_ws, size_t ws_size,
                              hipStream_t stream) {
    const float* X   = (const float*)d_in[0];   // [2048][64][300]
    const float* Wih = (const float*)d_in[1];   // [512][300]
    const float* Whh = (const float*)d_in[2];   // [512][512]
    const float* bih = (const float*)d_in[3];   // [512]
    const float* bhh = (const float*)d_in[4];   // [512]
    float* out = (float*)d_out;                 // [64][512]
    unsigned short* U3 = (unsigned short*)d_ws; // 128 MB, rec-lane order

    u_gemm<<<dim3(2048 * 8), dim3(256), 0, stream>>>(X, Wih, bih, bhh, U3);
    rnn_rec<<<dim3(4), dim3(512), 0, stream>>>(Whh, U3, out);
}